// Round 13
// baseline (457.106 us; speedup 1.0000x reference)
//
#include <hip/hip_runtime.h>
#include <hip/hip_bf16.h>
#include <stdint.h>

#define NTOK   8192
#define DM     1024
#define DFF    1024
#define NEXP   64
#define TOPK   2
#define NEXPAND (NTOK*TOPK)   // 16384
#define CAP    512            // (2*N)/E

#define UNROLL _Pragma("unroll")
#define SBAR() __builtin_amdgcn_sched_barrier(0)

typedef __attribute__((ext_vector_type(4))) float f32x4;
typedef __attribute__((ext_vector_type(8))) short bf16x8;
typedef __attribute__((ext_vector_type(4))) short short4v;

__device__ __forceinline__ short f2bf(float f) {
  __hip_bfloat16 h = __float2bfloat16(f);
  union { __hip_bfloat16 h; short s; } u; u.h = h; return u.s;
}
__device__ __forceinline__ float bf2f(short s) {
  union { float f; uint32_t u; } u; u.u = ((uint32_t)(uint16_t)s) << 16; return u.f;
}

__device__ __forceinline__ void gload16(const void* g, void* l) {
  __builtin_amdgcn_global_load_lds(
      (const __attribute__((address_space(1))) unsigned int*)g,
      (__attribute__((address_space(3))) unsigned int*)l, 16, 0, 0);
}

// ---------------- routing: exact sequential per-expert cumcount ----------------
__global__ __launch_bounds__(256) void k_route(const int* __restrict__ idx,
                                               int* __restrict__ slot_token,
                                               int* __restrict__ comb_slot) {
  const int ee = blockIdx.x;
  const int tid = threadIdx.x;
  const int lane = tid & 63;
  const int wv = tid >> 6;
  __shared__ int wsum[4];
  int base = 0;
  for (int it = 0; it < NEXPAND / 256; ++it) {
    int i = it * 256 + tid;
    bool m = (idx[i] == ee);
    unsigned long long bal = __ballot(m);
    int pre = __popcll(bal & ((1ull << lane) - 1ull));
    int wtot = __popcll(bal);
    if (lane == 0) wsum[wv] = wtot;
    __syncthreads();
    int wbase = 0, tot = 0;
UNROLL
    for (int w = 0; w < 4; ++w) { if (w < wv) wbase += wsum[w]; tot += wsum[w]; }
    if (m) {
      int pos = base + wbase + pre;
      if (pos < CAP) {
        comb_slot[i] = ee * CAP + pos;
        slot_token[ee * CAP + pos] = i >> 1;   // token index (k=2)
      } else {
        comb_slot[i] = -1;                      // dropped over capacity
      }
    }
    base += tot;
    __syncthreads();
  }
  int filled = base < CAP ? base : CAP;
  for (int p = filled + tid; p < CAP; p += 256) slot_token[ee * CAP + p] = -1;
}

// ---------------- dispatch: gather + f32->bf16 ----------------
__global__ __launch_bounds__(256) void k_dispatch(const float* __restrict__ hidden,
                                                  const int* __restrict__ slot_token,
                                                  short* __restrict__ xd) {
  int row = blockIdx.x;
  int tok = slot_token[row];
  int c = threadIdx.x * 4;
  short4v v;
  if (tok >= 0) {
    float4 f = *(const float4*)(hidden + (size_t)tok * DM + c);
    v[0] = f2bf(f.x); v[1] = f2bf(f.y); v[2] = f2bf(f.z); v[3] = f2bf(f.w);
  } else {
    v[0] = 0; v[1] = 0; v[2] = 0; v[3] = 0;
  }
  *(short4v*)(xd + (size_t)row * DM + c) = v;
}

// BK=64 m97-class structure. LDS tiles [row][64 bf16] (128B rows, 8 chunks of
// 16B); phys chunk = logical chunk ^ (row&7)  (the G4-documented fix).
// A DMA'd linear w/ pre-swizzled global source; B reg-staged, XOR write/read.
// ONE s_barrier per K-step (16 steps, half of BK=32's 32): body t issues
// A(t+1) [4 dma] then B(t+2) [32 loads], stages B(t+1) (compiler auto-wait
// vmcnt(36) drains those regs), MFMA(t) [32/wave], explicit vmcnt(32) drains
// A(t+1) leaving B(t+2) in flight, lgkm, barrier. Peeled t=14 (vmcnt 0) / 15.

// ---------------- GEMM1: act = silu(x@Wg) * (x@Wu) ----------------
// block 128 rows x (64g + 64u), 4 waves, wave 64r x (32g+32u)
__global__ __launch_bounds__(256, 2) void k_gemm1(const short* __restrict__ xd,
                                                  const float* __restrict__ gup,
                                                  short* __restrict__ act) {
  __shared__ short As[2][128 * 64];
  __shared__ short Bg[2][64 * 64];
  __shared__ short Bu[2][64 * 64];
  int bid0 = blockIdx.x;
  int bid = (bid0 & 7) * (4096 / 8) + (bid0 >> 3);   // XCD chunked swizzle
  const int e  = bid >> 6;
  const int mt = (bid >> 4) & 3;
  const int nt = bid & 15;
  const int tid = threadIdx.x;
  const int lane = tid & 63;
  const int wid = tid >> 6;
  const int wm = wid >> 1;   // 0..1
  const int wn = wid & 1;    // 0..1

  const short* Abase = xd + (size_t)(e * CAP + mt * 128) * DM;
  const float* Wg = gup + (size_t)e * DM * 2048 + nt * 64;

  // A staging: issue c in 0..3 covers rows c*32 + wid*8 + (lane>>3)
  const int arowloc = wid * 8 + (lane >> 3);
  const int asw = ((lane & 7) ^ (lane >> 3)) * 8;     // pre-swizzled src chunk
  // B gather: col per thread, 16 k-rows (2 chunks)
  const int bn = tid & 63;
  const int kq = tid >> 6;   // 0..3 -> k rows 16kq..16kq+15
  const int bsw = bn & 7;
  const int bo0 = bn * 64 + (((2 * kq)     ^ bsw) * 8);
  const int bo1 = bn * 64 + (((2 * kq + 1) ^ bsw) * 8);

  f32x4 accg[4][2], accu[4][2];
UNROLL
  for (int m = 0; m < 4; ++m)
UNROLL
    for (int n = 0; n < 2; ++n) { accg[m][n] = (f32x4)0.f; accu[m][n] = (f32x4)0.f; }

  float gvA[16], uvA[16], gvB[16], uvB[16];

#define G1_LOADA(BUF, K0)                                                      \
UNROLL                                                                         \
  for (int c = 0; c < 4; ++c)                                                  \
    gload16(Abase + (size_t)(c * 32 + arowloc) * DM + (K0) + asw,              \
            &As[BUF][c * 2048 + wid * 512]);

#define G1_LOADB(GD, UD, K0)                                                   \
  { const float* gp_ = Wg + (size_t)((K0) + 16 * kq) * 2048 + bn;              \
UNROLL                                                                         \
    for (int j = 0; j < 16; ++j) {                                             \
      GD[j] = gp_[(size_t)j * 2048]; UD[j] = gp_[(size_t)j * 2048 + 1024]; } }

#define G1_STAGEB(BUF, GR, UR)                                                 \
  { bf16x8 g0_ = { f2bf(GR[0]), f2bf(GR[1]), f2bf(GR[2]), f2bf(GR[3]),         \
                   f2bf(GR[4]), f2bf(GR[5]), f2bf(GR[6]), f2bf(GR[7]) };       \
    bf16x8 g1_ = { f2bf(GR[8]), f2bf(GR[9]), f2bf(GR[10]), f2bf(GR[11]),       \
                   f2bf(GR[12]), f2bf(GR[13]), f2bf(GR[14]), f2bf(GR[15]) };   \
    bf16x8 u0_ = { f2bf(UR[0]), f2bf(UR[1]), f2bf(UR[2]), f2bf(UR[3]),         \
                   f2bf(UR[4]), f2bf(UR[5]), f2bf(UR[6]), f2bf(UR[7]) };       \
    bf16x8 u1_ = { f2bf(UR[8]), f2bf(UR[9]), f2bf(UR[10]), f2bf(UR[11]),       \
                   f2bf(UR[12]), f2bf(UR[13]), f2bf(UR[14]), f2bf(UR[15]) };   \
    *(bf16x8*)&Bg[BUF][bo0] = g0_;  *(bf16x8*)&Bg[BUF][bo1] = g1_;             \
    *(bf16x8*)&Bu[BUF][bo0] = u0_;  *(bf16x8*)&Bu[BUF][bo1] = u1_; }

#define G1_MFMA(CUR)                                                           \
UNROLL                                                                         \
  for (int kh = 0; kh < 2; ++kh) {                                             \
    const int co_ = ((kh * 4 + (lane >> 4)) ^ (lane & 7)) * 8;                 \
    bf16x8 a_[4], bg_[2], bu_[2];                                              \
UNROLL                                                                         \
    for (int m = 0; m < 4; ++m)                                                \
      a_[m] = *(const bf16x8*)&As[CUR][(wm * 64 + m * 16 + (lane & 15)) * 64 + co_]; \
UNROLL                                                                         \
    for (int n = 0; n < 2; ++n) {                                              \
      bg_[n] = *(const bf16x8*)&Bg[CUR][(wn * 32 + n * 16 + (lane & 15)) * 64 + co_]; \
      bu_[n] = *(const bf16x8*)&Bu[CUR][(wn * 32 + n * 16 + (lane & 15)) * 64 + co_]; \
    }                                                                          \
UNROLL                                                                         \
    for (int m = 0; m < 4; ++m)                                                \
UNROLL                                                                         \
      for (int n = 0; n < 2; ++n) {                                            \
        accg[m][n] = __builtin_amdgcn_mfma_f32_16x16x32_bf16(a_[m], bg_[n], accg[m][n], 0, 0, 0); \
        accu[m][n] = __builtin_amdgcn_mfma_f32_16x16x32_bf16(a_[m], bu_[n], accu[m][n], 0, 0, 0); \
      }                                                                        \
  }

  // ---- prologue ----
  G1_LOADA(0, 0);          SBAR();
  G1_LOADB(gvA, uvA, 0);   SBAR();
  G1_LOADB(gvB, uvB, 64);  SBAR();
  asm volatile("s_waitcnt vmcnt(32)" ::: "memory");  // drain A0 + bvA; bvB in flight
  G1_STAGEB(0, gvA, uvA);
  asm volatile("s_waitcnt lgkmcnt(0)" ::: "memory");
  __builtin_amdgcn_s_barrier();
  SBAR();

#define G1_BODY(T, CUR, GR, UR, GW, UW) do {                                   \
    G1_LOADA((CUR) ^ 1, ((T) + 1) * 64);     SBAR();                           \
    G1_LOADB(GW, UW, ((T) + 2) * 64);        SBAR();                           \
    G1_STAGEB((CUR) ^ 1, GR, UR);  /* auto-wait drains B(t+1) regs */          \
    G1_MFMA(CUR);                                                              \
    asm volatile("s_waitcnt vmcnt(32)" ::: "memory");  /* drain A(t+1) */      \
    asm volatile("s_waitcnt lgkmcnt(0)" ::: "memory");                         \
    __builtin_amdgcn_s_barrier();                                              \
    SBAR();                                                                    \
  } while (0)

  for (int t2 = 0; t2 < 14; t2 += 2) {
    G1_BODY(t2,     0, gvB, uvB, gvA, uvA);
    G1_BODY(t2 + 1, 1, gvA, uvA, gvB, uvB);
  }
  // t=14: A(15) issue, no B(16); stage B(15); MFMA(14); drain all
  G1_LOADA(1, 15 * 64);    SBAR();
  G1_STAGEB(1, gvB, uvB);
  G1_MFMA(0);
  asm volatile("s_waitcnt vmcnt(0)" ::: "memory");
  asm volatile("s_waitcnt lgkmcnt(0)" ::: "memory");
  __builtin_amdgcn_s_barrier();
  SBAR();
  // t=15: MFMA only
  G1_MFMA(1);
#undef G1_BODY
#undef G1_LOADA
#undef G1_LOADB
#undef G1_STAGEB
#undef G1_MFMA

  // fused SwiGLU epilogue -> act bf16
  short* obase = act + (size_t)(e * CAP + mt * 128) * DFF + nt * 64;
UNROLL
  for (int m = 0; m < 4; ++m)
UNROLL
    for (int n = 0; n < 2; ++n)
UNROLL
      for (int j = 0; j < 4; ++j) {
        int rl = wm * 64 + m * 16 + (lane >> 4) * 4 + j;
        int cl = wn * 32 + n * 16 + (lane & 15);
        float g = accg[m][n][j];
        float u = accu[m][n][j];
        float s = (g / (1.f + __expf(-g))) * u;
        obase[(size_t)rl * DFF + cl] = f2bf(s);
      }
}

// ---------------- GEMM2: yd = act @ down (yd bf16) ----------------
// block 128 rows x 128 cols, 4 waves, wave 64x64
__global__ __launch_bounds__(256, 2) void k_gemm2(const short* __restrict__ act,
                                                  const float* __restrict__ down,
                                                  short* __restrict__ yd) {
  __shared__ short As[2][128 * 64];
  __shared__ short Bt[2][128 * 64];
  int bid0 = blockIdx.x;
  int bid = (bid0 & 7) * (2048 / 8) + (bid0 >> 3);   // XCD chunked swizzle
  const int e  = bid >> 5;
  const int mt = (bid >> 3) & 3;
  const int nt = bid & 7;
  const int tid = threadIdx.x;
  const int lane = tid & 63;
  const int wid = tid >> 6;
  const int wm = wid >> 1;   // 0..1
  const int wn = wid & 1;    // 0..1

  const short* Abase = act + (size_t)(e * CAP + mt * 128) * DFF;
  const float* Wb = down + (size_t)e * DFF * DM + nt * 128;

  const int arowloc = wid * 8 + (lane >> 3);
  const int asw = ((lane & 7) ^ (lane >> 3)) * 8;
  // B gather: col per thread, 32 k-rows (4 chunks)
  const int bn = tid & 127;
  const int kq = tid >> 7;   // 0..1 -> k rows 32kq..32kq+31
  const int bsw = bn & 7;
  const int bo0 = bn * 64 + (((4 * kq)     ^ bsw) * 8);
  const int bo1 = bn * 64 + (((4 * kq + 1) ^ bsw) * 8);
  const int bo2 = bn * 64 + (((4 * kq + 2) ^ bsw) * 8);
  const int bo3 = bn * 64 + (((4 * kq + 3) ^ bsw) * 8);

  f32x4 acc[4][4];
UNROLL
  for (int m = 0; m < 4; ++m)
UNROLL
    for (int n = 0; n < 4; ++n) acc[m][n] = (f32x4)0.f;

  float bvA[32], bvB[32];

#define G2_LOADA(BUF, K0)                                                      \
UNROLL                                                                         \
  for (int c = 0; c < 4; ++c)                                                  \
    gload16(Abase + (size_t)(c * 32 + arowloc) * DFF + (K0) + asw,             \
            &As[BUF][c * 2048 + wid * 512]);

#define G2_LOADB(DST, K0)                                                      \
  { const float* bp_ = Wb + (size_t)((K0) + 32 * kq) * DM + bn;                \
UNROLL                                                                         \
    for (int j = 0; j < 32; ++j) DST[j] = bp_[(size_t)j * DM]; }

#define G2_STAGEB(BUF, SRC)                                                    \
  { bf16x8 s0_ = { f2bf(SRC[0]),  f2bf(SRC[1]),  f2bf(SRC[2]),  f2bf(SRC[3]),  \
                   f2bf(SRC[4]),  f2bf(SRC[5]),  f2bf(SRC[6]),  f2bf(SRC[7]) };\
    bf16x8 s1_ = { f2bf(SRC[8]),  f2bf(SRC[9]),  f2bf(SRC[10]), f2bf(SRC[11]), \
                   f2bf(SRC[12]), f2bf(SRC[13]), f2bf(SRC[14]), f2bf(SRC[15]) };\
    bf16x8 s2_ = { f2bf(SRC[16]), f2bf(SRC[17]), f2bf(SRC[18]), f2bf(SRC[19]), \
                   f2bf(SRC[20]), f2bf(SRC[21]), f2bf(SRC[22]), f2bf(SRC[23]) };\
    bf16x8 s3_ = { f2bf(SRC[24]), f2bf(SRC[25]), f2bf(SRC[26]), f2bf(SRC[27]), \
                   f2bf(SRC[28]), f2bf(SRC[29]), f2bf(SRC[30]), f2bf(SRC[31]) };\
    *(bf16x8*)&Bt[BUF][bo0] = s0_;  *(bf16x8*)&Bt[BUF][bo1] = s1_;             \
    *(bf16x8*)&Bt[BUF][bo2] = s2_;  *(bf16x8*)&Bt[BUF][bo3] = s3_; }

#define G2_MFMA(CUR)                                                           \
UNROLL                                                                         \
  for (int kh = 0; kh < 2; ++kh) {                                             \
    const int co_ = ((kh * 4 + (lane >> 4)) ^ (lane & 7)) * 8;                 \
    bf16x8 a_[4], b_[4];                                                       \
UNROLL                                                                         \
    for (int m = 0; m < 4; ++m)                                                \
      a_[m] = *(const bf16x8*)&As[CUR][(wm * 64 + m * 16 + (lane & 15)) * 64 + co_]; \
UNROLL                                                                         \
    for (int n = 0; n < 4; ++n)                                                \
      b_[n] = *(const bf16x8*)&Bt[CUR][(wn * 64 + n * 16 + (lane & 15)) * 64 + co_]; \
UNROLL                                                                         \
    for (int m = 0; m < 4; ++m)                                                \
UNROLL                                                                         \
      for (int n = 0; n < 4; ++n)                                              \
        acc[m][n] = __builtin_amdgcn_mfma_f32_16x16x32_bf16(a_[m], b_[n], acc[m][n], 0, 0, 0); \
  }

  // ---- prologue ----
  G2_LOADA(0, 0);      SBAR();
  G2_LOADB(bvA, 0);    SBAR();
  G2_LOADB(bvB, 64);   SBAR();
  asm volatile("s_waitcnt vmcnt(32)" ::: "memory");
  G2_STAGEB(0, bvA);
  asm volatile("s_waitcnt lgkmcnt(0)" ::: "memory");
  __builtin_amdgcn_s_barrier();
  SBAR();

#define G2_BODY(T, CUR, BR, BW) do {                                           \
    G2_LOADA((CUR) ^ 1, ((T) + 1) * 64);     SBAR();                           \
    G2_LOADB(BW, ((T) + 2) * 64);            SBAR();                           \
    G2_STAGEB((CUR) ^ 1, BR);                                                  \
    G2_MFMA(CUR);                                                              \
    asm volatile("s_waitcnt vmcnt(32)" ::: "memory");                          \
    asm volatile("s_waitcnt lgkmcnt(0)" ::: "memory");                         \
    __builtin_amdgcn_s_barrier();                                              \
    SBAR();                                                                    \
  } while (0)

  for (int t2 = 0; t2 < 14; t2 += 2) {
    G2_BODY(t2,     0, bvB, bvA);
    G2_BODY(t2 + 1, 1, bvA, bvB);
  }
  G2_LOADA(1, 15 * 64);    SBAR();
  G2_STAGEB(1, bvB);
  G2_MFMA(0);
  asm volatile("s_waitcnt vmcnt(0)" ::: "memory");
  asm volatile("s_waitcnt lgkmcnt(0)" ::: "memory");
  __builtin_amdgcn_s_barrier();
  SBAR();
  G2_MFMA(1);
#undef G2_BODY
#undef G2_LOADA
#undef G2_LOADB
#undef G2_STAGEB
#undef G2_MFMA

  short* obase = yd + (size_t)(e * CAP + mt * 128) * DM + nt * 128;
UNROLL
  for (int m = 0; m < 4; ++m)
UNROLL
    for (int n = 0; n < 4; ++n)
UNROLL
      for (int j = 0; j < 4; ++j) {
        int rl = wm * 64 + m * 16 + (lane >> 4) * 4 + j;
        int cl = wn * 64 + n * 16 + (lane & 15);
        obase[(size_t)rl * DM + cl] = f2bf(acc[m][n][j]);
      }
}

// ---------------- combine: out[t] = sum_k w_k * yd[slot_k] (grid-stride) ----
__global__ __launch_bounds__(256) void k_combine(const int* __restrict__ comb_slot,
                                                 const float* __restrict__ topw,
                                                 const short* __restrict__ yd,
                                                 float* __restrict__ out) {
  int c = threadIdx.x * 4;
  for (int t = blockIdx.x; t < NTOK; t += 2048) {
    f32x4 acc = (f32x4)0.f;
UNROLL
    for (int j = 0; j < 2; ++j) {
      int s = comb_slot[2 * t + j];
      if (s >= 0) {
        float w = topw[2 * t + j];
        short4v v = *(const short4v*)(yd + (size_t)s * DM + c);
UNROLL
        for (int q = 0; q < 4; ++q) acc[q] += w * bf2f(v[q]);
      }
    }
    *(f32x4*)(out + (size_t)t * DM + c) = acc;
  }
}

extern "C" void kernel_launch(void* const* d_in, const int* in_sizes, int n_in,
                              void* d_out, int out_size, void* d_ws, size_t ws_size,
                              hipStream_t stream) {
  const float* hidden = (const float*)d_in[0];
  const int*   idx    = (const int*)d_in[1];
  const float* topw   = (const float*)d_in[2];
  const float* gup    = (const float*)d_in[3];
  const float* down   = (const float*)d_in[4];
  float* out = (float*)d_out;

  char* ws = (char*)d_ws;
  int*   slot_token = (int*)ws;                                   // 128KB
  int*   comb_slot  = (int*)(ws + 131072);                        // 64KB
  short* xd  = (short*)(ws + 131072 + 65536);                     // 64MB bf16
  short* act = xd + (size_t)NEXP * CAP * DM;                      // 64MB bf16
  short* yd  = act + (size_t)NEXP * CAP * DFF;                    // 64MB bf16

  k_route<<<NEXP, 256, 0, stream>>>(idx, slot_token, comb_slot);
  k_dispatch<<<NEXP * CAP, 256, 0, stream>>>(hidden, slot_token, xd);
  k_gemm1<<<4096, 256, 0, stream>>>(xd, gup, act);
  k_gemm2<<<2048, 256, 0, stream>>>(act, down, yd);
  k_combine<<<2048, 256, 0, stream>>>(comb_slot, topw, yd, out);
}

// Round 14
// 398.735 us; speedup vs baseline: 1.1464x; 1.1464x over previous
//
#include <hip/hip_runtime.h>
#include <hip/hip_bf16.h>
#include <stdint.h>

#define NTOK   8192
#define DM     1024
#define DFF    1024
#define NEXP   64
#define TOPK   2
#define NEXPAND (NTOK*TOPK)   // 16384
#define CAP    512            // (2*N)/E

#define UNROLL _Pragma("unroll")
#define SBAR() __builtin_amdgcn_sched_barrier(0)

typedef __attribute__((ext_vector_type(4))) float f32x4;
typedef __attribute__((ext_vector_type(8))) short bf16x8;
typedef __attribute__((ext_vector_type(4))) short short4v;

__device__ __forceinline__ short f2bf(float f) {
  __hip_bfloat16 h = __float2bfloat16(f);
  union { __hip_bfloat16 h; short s; } u; u.h = h; return u.s;
}
__device__ __forceinline__ float bf2f(short s) {
  union { float f; uint32_t u; } u; u.u = ((uint32_t)(uint16_t)s) << 16; return u.f;
}

__device__ __forceinline__ void gload16(const void* g, void* l) {
  __builtin_amdgcn_global_load_lds(
      (const __attribute__((address_space(1))) unsigned int*)g,
      (__attribute__((address_space(3))) unsigned int*)l, 16, 0, 0);
}

// ---------------- routing: exact sequential per-expert cumcount ----------------
__global__ __launch_bounds__(256) void k_route(const int* __restrict__ idx,
                                               int* __restrict__ slot_token,
                                               int* __restrict__ comb_slot) {
  const int ee = blockIdx.x;
  const int tid = threadIdx.x;
  const int lane = tid & 63;
  const int wv = tid >> 6;
  __shared__ int wsum[4];
  int base = 0;
  for (int it = 0; it < NEXPAND / 256; ++it) {
    int i = it * 256 + tid;
    bool m = (idx[i] == ee);
    unsigned long long bal = __ballot(m);
    int pre = __popcll(bal & ((1ull << lane) - 1ull));
    int wtot = __popcll(bal);
    if (lane == 0) wsum[wv] = wtot;
    __syncthreads();
    int wbase = 0, tot = 0;
UNROLL
    for (int w = 0; w < 4; ++w) { if (w < wv) wbase += wsum[w]; tot += wsum[w]; }
    if (m) {
      int pos = base + wbase + pre;
      if (pos < CAP) {
        comb_slot[i] = ee * CAP + pos;
        slot_token[ee * CAP + pos] = i >> 1;   // token index (k=2)
      } else {
        comb_slot[i] = -1;                      // dropped over capacity
      }
    }
    base += tot;
    __syncthreads();
  }
  int filled = base < CAP ? base : CAP;
  for (int p = filled + tid; p < CAP; p += 256) slot_token[ee * CAP + p] = -1;
}

// ---------------- dispatch: gather + f32->bf16 (grid-stride, 16 rows/block) ----
__global__ __launch_bounds__(256) void k_dispatch(const float* __restrict__ hidden,
                                                  const int* __restrict__ slot_token,
                                                  short* __restrict__ xd) {
  int c = threadIdx.x * 4;
  for (int row = blockIdx.x; row < NEXP * CAP; row += 2048) {
    int tok = slot_token[row];
    short4v v;
    if (tok >= 0) {
      float4 f = *(const float4*)(hidden + (size_t)tok * DM + c);
      v[0] = f2bf(f.x); v[1] = f2bf(f.y); v[2] = f2bf(f.z); v[3] = f2bf(f.w);
    } else {
      v[0] = 0; v[1] = 0; v[2] = 0; v[3] = 0;
    }
    *(short4v*)(xd + (size_t)row * DM + c) = v;
  }
}

// LDS tiles [row][32 bf16] (64B rows, 16B chunks), phys chunk = log ^ ((row>>1)&3).
// A DMA'd linear (pre-swizzled global source); B reg-staged, XOR write/read.
// DEPTH-2 A PIPELINE (R12, measured 400.9 clean): 3 LDS A-buffers; body t issues
// A(t+2)/B(t+2), MFMA(t), vmcnt(10) drains A(t+1)+bv(t+1), stages B(t+1), barrier.

// ---------------- GEMM1: act = silu(x@Wg) * (x@Wu) ----------------
// block 256 rows x (64 gate + 64 up), 8 waves, wave tile 64r x (32g+32u)
__global__ __launch_bounds__(512, 4) void k_gemm1(const short* __restrict__ xd,
                                                  const float* __restrict__ gup,
                                                  short* __restrict__ act) {
  __shared__ short As[3][256 * 32];
  __shared__ short Bg[2][64 * 32];
  __shared__ short Bu[2][64 * 32];
  int bid0 = blockIdx.x;
  int bid = (bid0 & 7) * (2048 / 8) + (bid0 >> 3);   // XCD chunked swizzle
  const int e  = bid >> 5;
  const int mt = (bid >> 4) & 1;
  const int nt = bid & 15;
  const int tid = threadIdx.x;
  const int lane = tid & 63;
  const int wid = tid >> 6;
  const int wm = wid >> 1;   // 0..3
  const int wn = wid & 1;    // 0..1

  const short* Abase = xd + (size_t)(e * CAP + mt * 256) * DM;
  const float* Wg = gup + (size_t)e * DM * 2048 + nt * 64;

  const int arowloc = wid * 16 + (lane >> 2);
  const int asw = ((lane & 3) ^ ((lane >> 3) & 3)) * 8;
  const int bn = tid & 63;          // column 0..63
  const int bq = tid >> 6;          // 0..7 -> rows 4bq..4bq+3
  const int boff = bn * 32 + (((bq >> 1) ^ ((bn >> 1) & 3)) * 8) + 4 * (bq & 1);
  const int co = (((lane >> 4) ^ ((lane >> 1) & 3))) * 8;

  f32x4 accg[4][2], accu[4][2];
UNROLL
  for (int m = 0; m < 4; ++m)
UNROLL
    for (int n = 0; n < 2; ++n) { accg[m][n] = (f32x4)0.f; accu[m][n] = (f32x4)0.f; }

  float gv0[4], uv0[4], gv1[4], uv1[4];

#define G1_LOADA(BUF, K0)                                                      \
  { gload16(Abase + (size_t)(arowloc) * DM + (K0) + asw, &As[BUF][wid * 512]); \
    gload16(Abase + (size_t)(128 + arowloc) * DM + (K0) + asw,                 \
            &As[BUF][4096 + wid * 512]); }

#define G1_LOADB(GD, UD, K0)                                                   \
  { const float* gp_ = Wg + (size_t)((K0) + 4 * bq) * 2048 + bn;               \
    GD[0] = gp_[0];    GD[1] = gp_[2048]; GD[2] = gp_[4096]; GD[3] = gp_[6144];\
    UD[0] = gp_[1024]; UD[1] = gp_[3072]; UD[2] = gp_[5120]; UD[3] = gp_[7168]; }

#define G1_STAGEB(BUF, GR, UR)                                                 \
  { short4v sg_ = { f2bf(GR[0]), f2bf(GR[1]), f2bf(GR[2]), f2bf(GR[3]) };      \
    short4v su_ = { f2bf(UR[0]), f2bf(UR[1]), f2bf(UR[2]), f2bf(UR[3]) };      \
    *(short4v*)&Bg[BUF][boff] = sg_;                                           \
    *(short4v*)&Bu[BUF][boff] = su_; }

#define G1_MFMA(AR, BR)                                                        \
  { bf16x8 a_[4], bg_[2], bu_[2];                                              \
UNROLL                                                                         \
    for (int m = 0; m < 4; ++m)                                                \
      a_[m] = *(const bf16x8*)&As[AR][(wm * 64 + m * 16 + (lane & 15)) * 32 + co]; \
UNROLL                                                                         \
    for (int n = 0; n < 2; ++n) {                                              \
      bg_[n] = *(const bf16x8*)&Bg[BR][(wn * 32 + n * 16 + (lane & 15)) * 32 + co]; \
      bu_[n] = *(const bf16x8*)&Bu[BR][(wn * 32 + n * 16 + (lane & 15)) * 32 + co]; \
    }                                                                          \
UNROLL                                                                         \
    for (int m = 0; m < 4; ++m)                                                \
UNROLL                                                                         \
      for (int n = 0; n < 2; ++n) {                                            \
        accg[m][n] = __builtin_amdgcn_mfma_f32_16x16x32_bf16(a_[m], bg_[n], accg[m][n], 0, 0, 0); \
        accu[m][n] = __builtin_amdgcn_mfma_f32_16x16x32_bf16(a_[m], bu_[n], accu[m][n], 0, 0, 0); \
      } }

  // ---- prologue: A0->As0, A1->As1, bv0, bv1; stage B0; barrier ----
  G1_LOADA(0, 0);    SBAR();
  G1_LOADA(1, 32);   SBAR();
  G1_LOADB(gv0, uv0, 0);   SBAR();
  G1_LOADB(gv1, uv1, 32);  SBAR();
  asm volatile("s_waitcnt vmcnt(8)" ::: "memory");   // drain A0,A1,bv0; bv1 in flight
  G1_STAGEB(0, gv0, uv0);
  asm volatile("s_waitcnt lgkmcnt(0)" ::: "memory");
  __builtin_amdgcn_s_barrier();
  SBAR();

#define G1_BODY(T, ARD, AWR, BRD, BWR, GR, UR, GW, UW) do {                    \
    G1_LOADA(AWR, ((T) + 2) * 32);           SBAR();                           \
    G1_LOADB(GW, UW, ((T) + 2) * 32);        SBAR();                           \
    G1_MFMA(ARD, BRD);                                                         \
    asm volatile("s_waitcnt vmcnt(10)" ::: "memory");                          \
    G1_STAGEB(BWR, GR, UR);                                                    \
    asm volatile("s_waitcnt lgkmcnt(0)" ::: "memory");                         \
    __builtin_amdgcn_s_barrier();                                              \
    SBAR();                                                                    \
  } while (0)

  for (int t6 = 0; t6 < 30; t6 += 6) {
    G1_BODY(t6,     0, 2, 0, 1, gv1, uv1, gv0, uv0);
    G1_BODY(t6 + 1, 1, 0, 1, 0, gv0, uv0, gv1, uv1);
    G1_BODY(t6 + 2, 2, 1, 0, 1, gv1, uv1, gv0, uv0);
    G1_BODY(t6 + 3, 0, 2, 1, 0, gv0, uv0, gv1, uv1);
    G1_BODY(t6 + 4, 1, 0, 0, 1, gv1, uv1, gv0, uv0);
    G1_BODY(t6 + 5, 2, 1, 1, 0, gv0, uv0, gv1, uv1);
  }
  // t=30: no issues; MFMA(30) As0,B0; vmcnt(0) drains bv(31); stage B(31)->B1
  G1_MFMA(0, 0);
  asm volatile("s_waitcnt vmcnt(0)" ::: "memory");
  G1_STAGEB(1, gv1, uv1);
  asm volatile("s_waitcnt lgkmcnt(0)" ::: "memory");
  __builtin_amdgcn_s_barrier();
  SBAR();
  // t=31: MFMA only
  G1_MFMA(1, 1);
#undef G1_BODY
#undef G1_LOADA
#undef G1_LOADB
#undef G1_STAGEB
#undef G1_MFMA

  // fused SwiGLU epilogue -> act bf16
  short* obase = act + (size_t)(e * CAP + mt * 256) * DFF + nt * 64;
UNROLL
  for (int m = 0; m < 4; ++m)
UNROLL
    for (int n = 0; n < 2; ++n)
UNROLL
      for (int j = 0; j < 4; ++j) {
        int rl = wm * 64 + m * 16 + (lane >> 4) * 4 + j;
        int cl = wn * 32 + n * 16 + (lane & 15);
        float g = accg[m][n][j];
        float u = accu[m][n][j];
        float s = (g / (1.f + __expf(-g))) * u;
        obase[(size_t)rl * DFF + cl] = f2bf(s);
      }
}

// ---------------- GEMM2: yd = act @ down (yd bf16) ----------------
// block 256 rows x 128 cols, 8 waves, wave tile 64x64
__global__ __launch_bounds__(512, 4) void k_gemm2(const short* __restrict__ act,
                                                  const float* __restrict__ down,
                                                  short* __restrict__ yd) {
  __shared__ short As[3][256 * 32];
  __shared__ short Bt[2][128 * 32];
  int bid0 = blockIdx.x;
  int bid = (bid0 & 7) * (1024 / 8) + (bid0 >> 3);   // XCD chunked swizzle
  const int e  = bid >> 4;
  const int mt = (bid >> 3) & 1;
  const int nt = bid & 7;
  const int tid = threadIdx.x;
  const int lane = tid & 63;
  const int wid = tid >> 6;
  const int wm = wid >> 1;   // 0..3
  const int wn = wid & 1;    // 0..1

  const short* Abase = act + (size_t)(e * CAP + mt * 256) * DFF;
  const float* Wb = down + (size_t)e * DFF * DM + nt * 128;

  const int arowloc = wid * 16 + (lane >> 2);
  const int asw = ((lane & 3) ^ ((lane >> 3) & 3)) * 8;
  const int bn = tid & 127;         // column 0..127
  const int bq = tid >> 7;          // 0..3 -> rows 8bq..8bq+7
  const int boff = bn * 32 + ((bq ^ ((bn >> 1) & 3)) * 8);
  const int co = (((lane >> 4) ^ ((lane >> 1) & 3))) * 8;

  f32x4 acc[4][4];
UNROLL
  for (int m = 0; m < 4; ++m)
UNROLL
    for (int n = 0; n < 4; ++n) acc[m][n] = (f32x4)0.f;

  float bv0[8], bv1[8];

#define G2_LOADA(BUF, K0)                                                      \
  { gload16(Abase + (size_t)(arowloc) * DFF + (K0) + asw, &As[BUF][wid * 512]);\
    gload16(Abase + (size_t)(128 + arowloc) * DFF + (K0) + asw,                \
            &As[BUF][4096 + wid * 512]); }

#define G2_LOADB(DST, K0)                                                      \
  { const float* bp_ = Wb + (size_t)((K0) + 8 * bq) * DM + bn;                 \
    DST[0] = bp_[0];        DST[1] = bp_[DM];     DST[2] = bp_[2 * DM];        \
    DST[3] = bp_[3 * DM];   DST[4] = bp_[4 * DM]; DST[5] = bp_[5 * DM];        \
    DST[6] = bp_[6 * DM];   DST[7] = bp_[7 * DM]; }

#define G2_STAGEB(BUF, SRC)                                                    \
  { bf16x8 sb_ = { f2bf(SRC[0]), f2bf(SRC[1]), f2bf(SRC[2]), f2bf(SRC[3]),     \
                   f2bf(SRC[4]), f2bf(SRC[5]), f2bf(SRC[6]), f2bf(SRC[7]) };   \
    *(bf16x8*)&Bt[BUF][boff] = sb_; }

#define G2_MFMA(AR, BR)                                                        \
  { bf16x8 a_[4], b_[4];                                                       \
UNROLL                                                                         \
    for (int m = 0; m < 4; ++m)                                                \
      a_[m] = *(const bf16x8*)&As[AR][(wm * 64 + m * 16 + (lane & 15)) * 32 + co]; \
UNROLL                                                                         \
    for (int n = 0; n < 4; ++n)                                                \
      b_[n] = *(const bf16x8*)&Bt[BR][(wn * 64 + n * 16 + (lane & 15)) * 32 + co]; \
UNROLL                                                                         \
    for (int m = 0; m < 4; ++m)                                                \
UNROLL                                                                         \
      for (int n = 0; n < 4; ++n)                                              \
        acc[m][n] = __builtin_amdgcn_mfma_f32_16x16x32_bf16(a_[m], b_[n], acc[m][n], 0, 0, 0); }

  // ---- prologue ----
  G2_LOADA(0, 0);    SBAR();
  G2_LOADA(1, 32);   SBAR();
  G2_LOADB(bv0, 0);  SBAR();
  G2_LOADB(bv1, 32); SBAR();
  asm volatile("s_waitcnt vmcnt(8)" ::: "memory");
  G2_STAGEB(0, bv0);
  asm volatile("s_waitcnt lgkmcnt(0)" ::: "memory");
  __builtin_amdgcn_s_barrier();
  SBAR();

#define G2_BODY(T, ARD, AWR, BRD, BWR, RR, RW) do {                            \
    G2_LOADA(AWR, ((T) + 2) * 32);   SBAR();                                   \
    G2_LOADB(RW, ((T) + 2) * 32);    SBAR();                                   \
    G2_MFMA(ARD, BRD);                                                         \
    asm volatile("s_waitcnt vmcnt(10)" ::: "memory");                          \
    G2_STAGEB(BWR, RR);                                                        \
    asm volatile("s_waitcnt lgkmcnt(0)" ::: "memory");                         \
    __builtin_amdgcn_s_barrier();                                              \
    SBAR();                                                                    \
  } while (0)

  for (int t6 = 0; t6 < 30; t6 += 6) {
    G2_BODY(t6,     0, 2, 0, 1, bv1, bv0);
    G2_BODY(t6 + 1, 1, 0, 1, 0, bv0, bv1);
    G2_BODY(t6 + 2, 2, 1, 0, 1, bv1, bv0);
    G2_BODY(t6 + 3, 0, 2, 1, 0, bv0, bv1);
    G2_BODY(t6 + 4, 1, 0, 0, 1, bv1, bv0);
    G2_BODY(t6 + 5, 2, 1, 1, 0, bv0, bv1);
  }
  G2_MFMA(0, 0);
  asm volatile("s_waitcnt vmcnt(0)" ::: "memory");
  G2_STAGEB(1, bv1);
  asm volatile("s_waitcnt lgkmcnt(0)" ::: "memory");
  __builtin_amdgcn_s_barrier();
  SBAR();
  G2_MFMA(1, 1);
#undef G2_BODY
#undef G2_LOADA
#undef G2_LOADB
#undef G2_STAGEB
#undef G2_MFMA

  short* obase = yd + (size_t)(e * CAP + mt * 256) * DM + nt * 128;
UNROLL
  for (int m = 0; m < 4; ++m)
UNROLL
    for (int n = 0; n < 4; ++n)
UNROLL
      for (int j = 0; j < 4; ++j) {
        int rl = wm * 64 + m * 16 + (lane >> 4) * 4 + j;
        int cl = wn * 64 + n * 16 + (lane & 15);
        obase[(size_t)rl * DM + cl] = f2bf(acc[m][n][j]);
      }
}

// ---------------- combine: out[t] = sum_k w_k * yd[slot_k] (grid-stride) ----
__global__ __launch_bounds__(256) void k_combine(const int* __restrict__ comb_slot,
                                                 const float* __restrict__ topw,
                                                 const short* __restrict__ yd,
                                                 float* __restrict__ out) {
  int c = threadIdx.x * 4;
  for (int t = blockIdx.x; t < NTOK; t += 2048) {
    f32x4 acc = (f32x4)0.f;
UNROLL
    for (int j = 0; j < 2; ++j) {
      int s = comb_slot[2 * t + j];
      if (s >= 0) {
        float w = topw[2 * t + j];
        short4v v = *(const short4v*)(yd + (size_t)s * DM + c);
UNROLL
        for (int q = 0; q < 4; ++q) acc[q] += w * bf2f(v[q]);
      }
    }
    *(f32x4*)(out + (size_t)t * DM + c) = acc;
  }
}

extern "C" void kernel_launch(void* const* d_in, const int* in_sizes, int n_in,
                              void* d_out, int out_size, void* d_ws, size_t ws_size,
                              hipStream_t stream) {
  const float* hidden = (const float*)d_in[0];
  const int*   idx    = (const int*)d_in[1];
  const float* topw   = (const float*)d_in[2];
  const float* gup    = (const float*)d_in[3];
  const float* down   = (const float*)d_in[4];
  float* out = (float*)d_out;

  char* ws = (char*)d_ws;
  int*   slot_token = (int*)ws;                                   // 128KB
  int*   comb_slot  = (int*)(ws + 131072);                        // 64KB
  short* xd  = (short*)(ws + 131072 + 65536);                     // 64MB bf16
  short* act = xd + (size_t)NEXP * CAP * DM;                      // 64MB bf16
  short* yd  = act + (size_t)NEXP * CAP * DFF;                    // 64MB bf16

  k_route<<<NEXP, 256, 0, stream>>>(idx, slot_token, comb_slot);
  k_dispatch<<<2048, 256, 0, stream>>>(hidden, slot_token, xd);
  k_gemm1<<<2048, 512, 0, stream>>>(xd, gup, act);
  k_gemm2<<<1024, 512, 0, stream>>>(act, down, yd);
  k_combine<<<2048, 256, 0, stream>>>(comb_slot, topw, yd, out);
}